// Round 2
// baseline (1565.399 us; speedup 1.0000x reference)
//
#include <hip/hip_runtime.h>

// TemporalLayer: T=64, N=2048, D=512, weight=0.5, causal attention, no sqrt(d) scale.
// Inputs and output are FP32 (reference dtypes). Internal pipeline is fp16 MFMA
// (v_mfma_f32_16x16x32_f16, fp32 accum): fp16 rounding at 2^-11 keeps the sharp
// softmax (sigma(scores)~22.6) well inside the 0.133 threshold.
// ws: 3x512x512 fp16 transposed Wq/Wk/Wv + 512x512 fp16 lin_w = 2 MB.
// fp16 out-scratch lives in the UPPER HALF of each node's own fp32 output slot
// (elt 65536*n + 32768), so ff_final's in-place fp32 writes only clobber scratch
// of its own node, after all reads (pre-read to regs + barrier) are done.

#define TT 64
#define NN 2048
#define DD 512

typedef _Float16 f16x8 __attribute__((ext_vector_type(8)));
typedef float    f32x4 __attribute__((ext_vector_type(4)));

#define MFMA16(a,b,c) __builtin_amdgcn_mfma_f32_16x16x32_f16((a),(b),(c),0,0,0)

// ---- Wq/Wk/Wv: f32 [d][e] -> fp16 [e][d]; lin_w: f32 [e][d] -> fp16 [e][d] ----
__global__ __launch_bounds__(256) void prep_weights(
    const float* __restrict__ Wq, const float* __restrict__ Wk,
    const float* __restrict__ Wv, const float* __restrict__ lw,
    _Float16* __restrict__ out)
{
  int gid = blockIdx.x * 256 + threadIdx.x;   // 4 * 512 * 64 groups of 8
  int mat = gid >> 15;
  int rem = gid & 32767;
  int e   = rem >> 6;
  int d0  = (rem & 63) << 3;
  union { _Float16 h[8]; uint4 u; } o;
  if (mat < 3) {
    const float* W = (mat == 0) ? Wq : (mat == 1) ? Wk : Wv;
    #pragma unroll
    for (int j = 0; j < 8; ++j)
      o.h[j] = (_Float16)W[(size_t)(d0 + j) * DD + e];   // transpose
  } else {
    #pragma unroll
    for (int j = 0; j < 8; ++j)
      o.h[j] = (_Float16)lw[(size_t)e * DD + d0 + j];    // plain convert
  }
  *(uint4*)(out + ((size_t)mat * DD * DD + (size_t)e * DD + d0)) = o.u;
}

// ---- fused per-node: temporal -> q,k -> scores -> softmax -> v -> out=attn@v ----
// grid = 2048 nodes, block = 512 (8 waves). LDS 55296 B -> 2 workgroups/CU.
// MFMA 16x16x32 f16 layouts: A[m=l&15][k=quad*8+j]; B from [n][k] storage, n=l&15;
// C/D: col=l&15, row=quad*4+reg.
__global__ __launch_bounds__(512) void attn_fused(
    const float* __restrict__ x, const float* __restrict__ pos,
    const _Float16* __restrict__ WqT, const _Float16* __restrict__ WkT,
    const _Float16* __restrict__ WvT, _Float16* __restrict__ outp)
{
  __shared__ char smem[55296];
  char* const tst = smem;            // [64][40] f16, stride 80 B (t block, 32 k + 8 pad)
  char* const wst = smem + 5120;     // [512][40] f16, stride 80 B (weight block) -- aliased:
  char* const qdp = smem + 5120;     //   [64][136] f16, stride 272 B (q dump, 128 cols)
  char* const kdp = smem + 22528;    //   [64][136] f16, stride 272 B (k dump)
  char* const scb = smem + 5120;     //   [64][68] f32, stride 272 B (scores)
  char* const vdp = smem + 5120;     //   8 x [32][72] f16, stride 144 B (per-wave vT dump)
  char* const atn = smem + 46080;    // [64][72] f16, stride 144 B (attn probs)

  const int n    = blockIdx.x;
  const int tid  = threadIdx.x;
  const int wid  = tid >> 6;
  const int lane = tid & 63;
  const int quad = lane >> 4;
  const int l15  = lane & 15;
  const size_t scrbase = (size_t)n * 65536 + 32768;   // fp16 scratch in node's out slot

  auto stage_t = [&](int kb){   // t[row][kb*32..+31] = fp16(x+pos), fp32 inputs
    const int row = tid >> 3, i = tid & 7;
    f32x4 xv = *(const f32x4*)(x + ((size_t)row * NN + n) * DD + kb*32 + 4*i);
    f32x4 pv = *(const f32x4*)(pos + (size_t)row * DD + kb*32 + 4*i);
    union { _Float16 h[4]; unsigned long long u; } o;
    #pragma unroll
    for (int j = 0; j < 4; ++j) o.h[j] = (_Float16)(xv[j] + pv[j]);
    *(unsigned long long*)(tst + row*80 + 8*i) = o.u;
  };

  f32x4 sacc[2] = {};   // this wave's 2 score tiles, accumulated over all 512 e

  for (int ph = 0; ph < 2; ++ph) {          // e in [ph*256, ph*256+256)
    f32x4 acc[4][4] = {};                   // q- or k-slice [64 t][64 e] of this wave
    const bool isK = (wid >= 4);
    const int  esl = wid & 3;
    const int  wrow = (isK ? 256 : 0) + esl * 64;
    const _Float16* Aq = WqT + (size_t)ph * 131072;
    const _Float16* Ak = WkT + (size_t)ph * 131072;

    for (int kb = 0; kb < 16; ++kb) {       // K blocks of 32
      __syncthreads();
      stage_t(kb);
      { // Wstage rows 0..255 = WqT[ph half], rows 256..511 = WkT[ph half]
        const _Float16* src = (tid < 256) ? (Aq + (size_t)tid * DD + kb*32)
                                          : (Ak + (size_t)(tid - 256) * DD + kb*32);
        const uint4* s4 = (const uint4*)src;
        uint4* d4 = (uint4*)(wst + tid * 80);
        d4[0]=s4[0]; d4[1]=s4[1]; d4[2]=s4[2]; d4[3]=s4[3];
      }
      __syncthreads();
      f16x8 af[4];
      #pragma unroll
      for (int rt = 0; rt < 4; ++rt)
        af[rt] = *(const f16x8*)(tst + (16*rt + l15)*80 + quad*16);
      #pragma unroll
      for (int ct = 0; ct < 4; ++ct) {
        f16x8 bf = *(const f16x8*)(wst + (wrow + 16*ct + l15)*80 + quad*16);
        #pragma unroll
        for (int rt = 0; rt < 4; ++rt)
          acc[rt][ct] = MFMA16(af[rt], bf, acc[rt][ct]);
      }
    }

    // dump 128-col blocks of q,k -> LDS, accumulate scores += q_c @ k_c^T
    for (int r = 0; r < 2; ++r) {
      __syncthreads();
      if ((esl >> 1) == r) {
        char* dst = isK ? kdp : qdp;
        const int colbase = (esl & 1) * 64;
        #pragma unroll
        for (int rt = 0; rt < 4; ++rt)
          #pragma unroll
          for (int ct = 0; ct < 4; ++ct)
            #pragma unroll
            for (int rg = 0; rg < 4; ++rg)
              *(_Float16*)(dst + (16*rt + quad*4 + rg)*272 + (colbase + 16*ct + l15)*2)
                  = (_Float16)acc[rt][ct][rg];
      }
      __syncthreads();
      const int srt = wid >> 1, sct0 = (wid & 1) * 2;
      #pragma unroll
      for (int ks = 0; ks < 4; ++ks) {
        f16x8 aq = *(const f16x8*)(qdp + (16*srt + l15)*272 + ks*64 + quad*16);
        #pragma unroll
        for (int j = 0; j < 2; ++j) {
          f16x8 bk = *(const f16x8*)(kdp + (16*(sct0+j) + l15)*272 + ks*64 + quad*16);
          sacc[j] = MFMA16(aq, bk, sacc[j]);
        }
      }
    }
  }

  // scores -> LDS (f32), causal softmax, attn probs (fp16) -> atn
  __syncthreads();
  {
    const int srt = wid >> 1, sct0 = (wid & 1) * 2;
    #pragma unroll
    for (int j = 0; j < 2; ++j)
      #pragma unroll
      for (int rg = 0; rg < 4; ++rg)
        *(float*)(scb + (16*srt + quad*4 + rg)*272 + (16*(sct0+j) + l15)*4) = sacc[j][rg];
  }
  __syncthreads();
  {
    const int row = tid >> 3, i = tid & 7;   // 8 threads per row, 8 cols each
    f32x4 s0 = *(const f32x4*)(scb + row*272 + 32*i);
    f32x4 s1 = *(const f32x4*)(scb + row*272 + 32*i + 16);
    float s[8] = { s0[0],s0[1],s0[2],s0[3], s1[0],s1[1],s1[2],s1[3] };
    float m = -3.0e38f;
    #pragma unroll
    for (int j = 0; j < 8; ++j) if (8*i + j <= row) m = fmaxf(m, s[j]);
    m = fmaxf(m, __shfl_xor(m, 1));
    m = fmaxf(m, __shfl_xor(m, 2));
    m = fmaxf(m, __shfl_xor(m, 4));
    float e[8]; float sum = 0.f;
    #pragma unroll
    for (int j = 0; j < 8; ++j) {
      e[j] = (8*i + j <= row) ? __expf(s[j] - m) : 0.f;   // NEG_BIG mask == exact zero
      sum += e[j];
    }
    sum += __shfl_xor(sum, 1);
    sum += __shfl_xor(sum, 2);
    sum += __shfl_xor(sum, 4);
    const float inv = 1.0f / sum;
    union { _Float16 h[8]; uint4 u; } o;
    #pragma unroll
    for (int j = 0; j < 8; ++j) o.h[j] = (_Float16)(e[j] * inv);
    *(uint4*)(atn + row*144 + 16*i) = o.u;
  }

  // V projection: wave w owns v[:, 64w..64w+63]
  f32x4 vacc[4][4] = {};
  for (int kb = 0; kb < 16; ++kb) {
    __syncthreads();
    stage_t(kb);
    {
      const _Float16* src = WvT + (size_t)tid * DD + kb*32;
      const uint4* s4 = (const uint4*)src;
      uint4* d4 = (uint4*)(wst + tid * 80);
      d4[0]=s4[0]; d4[1]=s4[1]; d4[2]=s4[2]; d4[3]=s4[3];
    }
    __syncthreads();
    f16x8 af[4];
    #pragma unroll
    for (int rt = 0; rt < 4; ++rt)
      af[rt] = *(const f16x8*)(tst + (16*rt + l15)*80 + quad*16);
    #pragma unroll
    for (int ct = 0; ct < 4; ++ct) {
      f16x8 bf = *(const f16x8*)(wst + (wid*64 + 16*ct + l15)*80 + quad*16);
      #pragma unroll
      for (int rt = 0; rt < 4; ++rt)
        vacc[rt][ct] = MFMA16(af[rt], bf, vacc[rt][ct]);
    }
  }

  // out = attn @ v, computed transposed (D[m=d][n=t]) so stores pack 4 consecutive d.
  __syncthreads();   // Wv stage reads done before vdump aliases wst
  char* const vd = vdp + wid * 4608;   // wave-private vT dump [32][72]
  #pragma unroll
  for (int h = 0; h < 2; ++h) {
    #pragma unroll
    for (int c = 0; c < 2; ++c) {
      const int ct = 2*h + c;
      #pragma unroll
      for (int rt = 0; rt < 4; ++rt)
        #pragma unroll
        for (int rg = 0; rg < 4; ++rg)
          *(_Float16*)(vd + (16*c + l15)*144 + (16*rt + quad*4 + rg)*2)
              = (_Float16)vacc[rt][ct][rg];
    }
    f32x4 oacc[2][4] = {};
    #pragma unroll
    for (int ks = 0; ks < 2; ++ks) {
      f16x8 av[2];
      #pragma unroll
      for (int mt = 0; mt < 2; ++mt)
        av[mt] = *(const f16x8*)(vd + (16*mt + l15)*144 + ks*64 + quad*16);
      #pragma unroll
      for (int nt = 0; nt < 4; ++nt) {
        f16x8 ba = *(const f16x8*)(atn + (16*nt + l15)*144 + ks*64 + quad*16);
        #pragma unroll
        for (int mt = 0; mt < 2; ++mt)
          oacc[mt][nt] = MFMA16(av[mt], ba, oacc[mt][nt]);
      }
    }
    #pragma unroll
    for (int mt = 0; mt < 2; ++mt)
      #pragma unroll
      for (int nt = 0; nt < 4; ++nt) {
        const int d0 = 64*wid + 32*h + 16*mt + quad*4;
        const int tq = 16*nt + l15;
        union { _Float16 h4[4]; uint2 u; } o;
        #pragma unroll
        for (int rg = 0; rg < 4; ++rg) o.h4[rg] = (_Float16)oacc[mt][nt][rg];
        *(uint2*)(outp + scrbase + (size_t)tq * DD + d0) = o.u;   // fp16 scratch
      }
  }
}

// ---- ff = relu(out @ lin_w^T + b); y = 0.5*(ff+out) + (x+pos), fp32 output ----
// ffT[e][t] (A = lin_w fp16 rows [e][d], k-contiguous). In-place on d_out: fp32
// writes clobber this node's own fp16 scratch, so pre-read scratch -> regs first.
__global__ __launch_bounds__(512) void ff_final(
    const _Float16* outp, const float* __restrict__ x,
    const float* __restrict__ pos, const _Float16* __restrict__ lwh,
    const float* __restrict__ lb, float* y)
{
  __shared__ char smem[46080];
  char* const ost = smem;          // [64][40] f16 stride 80 (out block)
  char* const lst = smem + 5120;   // [512][40] f16 stride 80 (lin_w block)

  const int n = blockIdx.x;
  const int tid = threadIdx.x;
  const int wid = tid >> 6, lane = tid & 63, quad = lane >> 4, l15 = lane & 15;
  const size_t scrbase = (size_t)n * 65536 + 32768;

  f32x4 acc[4][4] = {};            // ffT [64 e of this wave][64 t]
  for (int kb = 0; kb < 16; ++kb) {
    __syncthreads();
    {
      const int row = tid >> 3, i = tid & 7;
      *(unsigned long long*)(ost + row*80 + 8*i) =
          *(const unsigned long long*)(outp + scrbase + (size_t)row * DD + kb*32 + 4*i);
    }
    {
      const _Float16* src = lwh + (size_t)tid * DD + kb*32;
      const uint4* s4 = (const uint4*)src;
      uint4* d4 = (uint4*)(lst + tid * 80);
      d4[0]=s4[0]; d4[1]=s4[1]; d4[2]=s4[2]; d4[3]=s4[3];
    }
    __syncthreads();
    f16x8 af[4];
    #pragma unroll
    for (int mt = 0; mt < 4; ++mt)
      af[mt] = *(const f16x8*)(lst + (wid*64 + 16*mt + l15)*80 + quad*16);
    #pragma unroll
    for (int nt = 0; nt < 4; ++nt) {
      f16x8 bo = *(const f16x8*)(ost + (16*nt + l15)*80 + quad*16);
      #pragma unroll
      for (int mt = 0; mt < 4; ++mt)
        acc[mt][nt] = MFMA16(af[mt], bo, acc[mt][nt]);
    }
  }

  // Phase 1: pre-read ALL of this lane's scratch out-values into registers.
  uint2 ovv[4][4];
  #pragma unroll
  for (int mt = 0; mt < 4; ++mt) {
    const int e0 = wid*64 + 16*mt + quad*4;
    #pragma unroll
    for (int nt = 0; nt < 4; ++nt) {
      const int tq = 16*nt + l15;
      ovv[mt][nt] = *(const uint2*)(outp + scrbase + (size_t)tq * DD + e0);
    }
  }
  __syncthreads();   // drains vmcnt: every scratch read done before any fp32 write

  // Phase 2: epilogue + fp32 writes (these overwrite the node's scratch bytes).
  #pragma unroll
  for (int mt = 0; mt < 4; ++mt) {
    const int e0 = wid*64 + 16*mt + quad*4;
    f32x4 bias = *(const f32x4*)(lb + e0);
    #pragma unroll
    for (int nt = 0; nt < 4; ++nt) {
      const int tq = 16*nt + l15;
      const size_t base = ((size_t)n * TT + tq) * DD + e0;
      union { _Float16 h4[4]; uint2 u; } ov;
      ov.u = ovv[mt][nt];
      f32x4 xv = *(const f32x4*)(x + ((size_t)tq * NN + n) * DD + e0);
      f32x4 pv = *(const f32x4*)(pos + (size_t)tq * DD + e0);
      f32x4 ro;
      #pragma unroll
      for (int rg = 0; rg < 4; ++rg) {
        float ff = acc[mt][nt][rg] + bias[rg];
        ff = ff > 0.f ? ff : 0.f;
        ro[rg] = 0.5f * (ff + (float)ov.h4[rg]) + xv[rg] + pv[rg];  // exact fp32 temporal
      }
      *(f32x4*)(y + base) = ro;
    }
  }
}

extern "C" void kernel_launch(void* const* d_in, const int* in_sizes, int n_in,
                              void* d_out, int out_size, void* d_ws, size_t ws_size,
                              hipStream_t stream) {
  (void)in_sizes; (void)n_in; (void)out_size; (void)ws_size;
  const float* x   = (const float*)d_in[0];
  const float* pos = (const float*)d_in[1];
  const float* Wq  = (const float*)d_in[2];
  const float* Wk  = (const float*)d_in[3];
  const float* Wv  = (const float*)d_in[4];
  const float* lw  = (const float*)d_in[5];
  const float* lb  = (const float*)d_in[6];
  _Float16* wsW = (_Float16*)d_ws;   // 4 * 262144 fp16 = 2 MB

  prep_weights<<<512, 256, 0, stream>>>(Wq, Wk, Wv, lw, wsW);
  attn_fused<<<2048, 512, 0, stream>>>(x, pos, wsW, wsW + 262144, wsW + 524288,
                                       (_Float16*)d_out);
  ff_final<<<2048, 512, 0, stream>>>((const _Float16*)d_out, x, pos,
                                     wsW + 786432, lb, (float*)d_out);
}